// Round 5
// baseline (400.653 us; speedup 1.0000x reference)
//
#include <hip/hip_runtime.h>
#include <hip/hip_bf16.h>
#include <cstdint>
#include <cstddef>

using bf16 = __hip_bfloat16;
typedef __attribute__((ext_vector_type(8))) short bf16x8;   // 8 bf16 (MFMA A/B frag)
typedef __attribute__((ext_vector_type(4))) float f32x4;    // 16x16 MFMA C/D frag
typedef __attribute__((ext_vector_type(16))) float f32x16;  // 32x32 MFMA C/D frag

#define B_    4
#define LQ_   1024
#define LKV_  2048
#define QDIM_ 1024
#define KDIM_ 768
#define ODIM_ 1024
#define H_    16
#define HD_   64

// ---------------------------------------------------------------------------
// async global -> LDS, 16B per lane (wave-uniform LDS base + lane*16)
// ---------------------------------------------------------------------------
__device__ __forceinline__ void async_cp16(const void* g, void* l) {
  __builtin_amdgcn_global_load_lds(
      (const __attribute__((address_space(1))) void*)g,
      (__attribute__((address_space(3))) void*)l, 16, 0, 0);
}

// pack two f32 -> one u32 of 2 bf16 (lo = a, hi = b)
__device__ __forceinline__ unsigned cvtpk(float a, float b) {
  unsigned r;
  asm("v_cvt_pk_bf16_f32 %0, %1, %2" : "=v"(r) : "v"(a), "v"(b));
  return r;
}

__device__ __forceinline__ float fast_exp2(float x) {
#if __has_builtin(__builtin_amdgcn_exp2f)
  return __builtin_amdgcn_exp2f(x);
#else
  return exp2f(x);
#endif
}

__device__ __forceinline__ bf16x8 make_frag(unsigned w0, unsigned w1,
                                            unsigned w2, unsigned w3) {
  union { unsigned u[4]; bf16x8 v; } u;
  u.u[0] = w0; u.u[1] = w1; u.u[2] = w2; u.u[3] = w3;
  return u.v;
}

// ---------------------------------------------------------------------------
// mask normalize: input may be 1-byte bools or int32 0/1; emit float 1.0=keep,
// 0.0=masked. Detection: int32 0/1 data has all bytes at off%4!=0 zero.
// ---------------------------------------------------------------------------
__global__ void mask_prep(const void* __restrict__ mraw,
                          float* __restrict__ mf, int n) {
  __shared__ int fmt8;
  const int tid = threadIdx.x;
  if (tid == 0) fmt8 = 0;
  __syncthreads();
  const unsigned char* b = (const unsigned char*)mraw;
  int local = 0;
  for (int i = tid; i < n; i += 256)
    if ((i & 3) != 0 && b[i] != 0) local = 1;
  if (local) atomicOr(&fmt8, 1);
  __syncthreads();
  const int is8 = fmt8;
  const int* w = (const int*)mraw;
  for (int i = tid; i < n; i += 256) {
    int m = is8 ? (int)b[i] : (w[i] != 0);
    mf[i] = m ? 0.f : 1.f;   // True = masked -> 0 multiplier
  }
}

// ---------------------------------------------------------------------------
// fp32 -> bf16 elementwise convert
// ---------------------------------------------------------------------------
struct alignas(8) bf4 { bf16 x[4]; };

__global__ void cvt_f32_to_bf16(const float* __restrict__ in,
                                bf16* __restrict__ out, int n4) {
  int i = blockIdx.x * blockDim.x + threadIdx.x;
  if (i >= n4) return;
  float4 v = reinterpret_cast<const float4*>(in)[i];
  bf4 r;
  r.x[0] = __float2bfloat16(v.x);
  r.x[1] = __float2bfloat16(v.y);
  r.x[2] = __float2bfloat16(v.z);
  r.x[3] = __float2bfloat16(v.w);
  *reinterpret_cast<bf4*>(out + (size_t)i * 4) = r;
}

// ---------------------------------------------------------------------------
// weight transpose + convert: W [K][N] fp32  ->  WT [N][K] bf16
// ---------------------------------------------------------------------------
__global__ void wtrans(const float* __restrict__ W, bf16* __restrict__ WT,
                       int K, int N) {
  __shared__ bf16 t[64][65];
  const int n0 = blockIdx.x * 64, k0 = blockIdx.y * 64;
  const int tid = threadIdx.x;
#pragma unroll
  for (int i = 0; i < 16; ++i) {
    int idx = tid + i * 256;
    int nn = idx & 63, kk = idx >> 6;
    t[kk][nn] = __float2bfloat16(W[(size_t)(k0 + kk) * N + n0 + nn]);
  }
  __syncthreads();
#pragma unroll
  for (int i = 0; i < 16; ++i) {
    int idx = tid + i * 256;
    int kk = idx & 63, nn = idx >> 6;
    WT[(size_t)(n0 + nn) * K + k0 + kk] = t[kk][nn];
  }
}

// ---------------------------------------------------------------------------
// V transpose: vp [B][LKV][ODIM] bf16 -> vT [B][H][HD][LKV] bf16
// ---------------------------------------------------------------------------
__global__ void vtrans(const bf16* __restrict__ vp, bf16* __restrict__ vT) {
  __shared__ bf16 t[64][65];
  const int kv0 = blockIdx.x * 64, h = blockIdx.y, b = blockIdx.z;
  const int tid = threadIdx.x;
#pragma unroll
  for (int i = 0; i < 16; ++i) {
    int idx = tid + i * 256;
    int hd = idx & 63, kv = idx >> 6;
    t[kv][hd] = vp[(size_t)(b * LKV_ + kv0 + kv) * ODIM_ + h * HD_ + hd];
  }
  __syncthreads();
#pragma unroll
  for (int i = 0; i < 16; ++i) {
    int idx = tid + i * 256;
    int kv = idx & 63, nn = idx >> 6;
    vT[(size_t)((b * H_ + h) * HD_ + nn) * LKV_ + kv0 + kv] = t[kv][nn];
  }
}

// ---------------------------------------------------------------------------
// GEMM: C[M][N] = A[M][K] @ BT[N][K]^T + bias  (unchanged)
// ---------------------------------------------------------------------------
template <int OUT_BF16>
__launch_bounds__(256, 2)
__global__ void gemm_bt(const bf16* __restrict__ A, const bf16* __restrict__ BT,
                        const float* __restrict__ bias, void* __restrict__ Cout,
                        int M, int N, int K) {
  __shared__ bf16 As[128 * 64];
  __shared__ bf16 Bs[128 * 64];
  const int tid = threadIdx.x;
  const int lane = tid & 63, w = tid >> 6;
  const int wr = w >> 1, wc = w & 1;
  const int lr = lane & 15, lk = lane >> 4;
  const int m0 = blockIdx.y * 128, n0 = blockIdx.x * 128;

  f32x4 acc[4][4];
#pragma unroll
  for (int m = 0; m < 4; ++m)
#pragma unroll
    for (int n = 0; n < 4; ++n) acc[m][n] = (f32x4){0.f, 0.f, 0.f, 0.f};

  const int nk = K >> 6;
  for (int kt = 0; kt < nk; ++kt) {
    const int k0 = kt << 6;
#pragma unroll
    for (int i = 0; i < 4; ++i) {
      const int c = tid + i * 256;
      const int row = c >> 3, cc = c & 7;
      const int sc = cc ^ (row & 7);
      async_cp16(A + (size_t)(m0 + row) * K + k0 + sc * 8, As + c * 8);
    }
#pragma unroll
    for (int i = 0; i < 4; ++i) {
      const int c = tid + i * 256;
      const int row = c >> 3, cc = c & 7;
      const int sc = cc ^ (row & 7);
      async_cp16(BT + (size_t)(n0 + row) * K + k0 + sc * 8, Bs + c * 8);
    }
    asm volatile("s_waitcnt vmcnt(0)" ::: "memory");
    __syncthreads();

    bf16x8 af[4][2], bfr[4][2];
#pragma unroll
    for (int m = 0; m < 4; ++m)
#pragma unroll
      for (int ks = 0; ks < 2; ++ks) {
        const int r = wr * 64 + m * 16 + lr;
        af[m][ks] = *(const bf16x8*)((const char*)As + r * 128 +
                                     ((ks * 64 + lk * 16) ^ ((r & 7) << 4)));
      }
#pragma unroll
    for (int n = 0; n < 4; ++n)
#pragma unroll
      for (int ks = 0; ks < 2; ++ks) {
        const int r = wc * 64 + n * 16 + lr;
        bfr[n][ks] = *(const bf16x8*)((const char*)Bs + r * 128 +
                                      ((ks * 64 + lk * 16) ^ ((r & 7) << 4)));
      }
#pragma unroll
    for (int m = 0; m < 4; ++m)
#pragma unroll
      for (int n = 0; n < 4; ++n)
#pragma unroll
        for (int ks = 0; ks < 2; ++ks)
          acc[m][n] = __builtin_amdgcn_mfma_f32_16x16x32_bf16(
              af[m][ks], bfr[n][ks], acc[m][n], 0, 0, 0);
    __syncthreads();
  }

#pragma unroll
  for (int m = 0; m < 4; ++m)
#pragma unroll
    for (int n = 0; n < 4; ++n)
#pragma unroll
      for (int r4 = 0; r4 < 4; ++r4) {
        const int row = m0 + wr * 64 + m * 16 + lk * 4 + r4;
        const int col = n0 + wc * 64 + n * 16 + lr;
        float v = acc[m][n][r4] + bias[col];
        if (OUT_BF16)
          ((bf16*)Cout)[(size_t)row * N + col] = __float2bfloat16(v);
        else
          ((float*)Cout)[(size_t)row * N + col] = v;
      }
}

// ---------------------------------------------------------------------------
// Flash attention v3: swapped-operand 32x32x16 MFMA, in-register softmax,
// zero LDS, no barriers, and SIGMA-PERMUTED K rows so that the S registers
// come out directly in PV A-fragment order (no permlane/shfl repack).
//   kv axis is processed in permuted order sigma; softmax and sum are
//   order-agnostic; P reg r pairs with V rows in natural order by design:
//   s0 reg r (half hi) = P[q=l31][kv = (r<8 ? 8*hi+r : 8+8*hi+r)] (+32 for s1)
//   => pa[ks] elem j = P[q][16*ks + 8*hi + j] = exact A-layout.
// Defer-max (THR=11, log2 domain); mask as x{0,1} after exp.
// Grid: 512 blocks, d%8 = XCD; 8 (b,h) pairs per XCD -> K/V set = 4MB = L2.
// ---------------------------------------------------------------------------
__launch_bounds__(256, 2)
__global__ void attn3(const bf16* __restrict__ qp, const bf16* __restrict__ kp,
                      const bf16* __restrict__ vT, const float* __restrict__ mf,
                      bf16* __restrict__ att) {
  const int tid = threadIdx.x;
  const int w = tid >> 6, l = tid & 63;
  const int l31 = l & 31, hi = l >> 5;
  const int d = blockIdx.x;
  const int hb = (d & 7) * 8 + ((d >> 3) & 7);  // XCD-chunked (b,h)
  const int qt = d >> 6;
  const int h = hb & 15, b = hb >> 4;
  const int q0 = qt * 128 + w * 32;

  // sigma: A-row m (=l31) loads physical K row sigma(m)
  const int rr = (l31 & 3) + 4 * (l31 >> 3);
  const int hh = (l31 >> 2) & 1;
  const int sig = (rr < 8) ? (8 * hh + rr) : (8 + 8 * hh + rr);

  // Q fragments (B-operand): lane holds Q[q0+l31][hd = ks*16 + hi*8 + j]
  bf16x8 qf[4];
  {
    const bf16* qb =
        qp + (size_t)(b * LQ_ + q0 + l31) * ODIM_ + h * HD_ + hi * 8;
#pragma unroll
    for (int ks = 0; ks < 4; ++ks) qf[ks] = *(const bf16x8*)(qb + ks * 16);
  }
  // K base (sigma-permuted row), col = ks*16 + hi*8
  const bf16* kp0 = kp + (size_t)(b * LKV_ + sig) * ODIM_ + h * HD_ + hi * 8;
  // V^T base: row hd = l31 (+32 for oacc1), col kv = ks*16 + hi*8
  const bf16* vp0 = vT + (size_t)((b * H_ + h) * HD_ + l31) * LKV_ + hi * 8;
  const float* mp = mf + b * LKV_ + hi * 8;

  f32x16 oacc0, oacc1;
#pragma unroll
  for (int r = 0; r < 16; ++r) { oacc0[r] = 0.f; oacc1[r] = 0.f; }
  float m_ = -1e30f, l_ = 0.f;
  const float csc = 0.125f * 1.4426950408889634f;  // scale * log2(e)

  for (int t = 0; t < LKV_ / 64; ++t) {
    // ---- QK^T (swapped): s0/s1 = S^T for kv sub-blocks 0/1 of this 64-tile
    f32x16 s0, s1;
#pragma unroll
    for (int r = 0; r < 16; ++r) { s0[r] = 0.f; s1[r] = 0.f; }
#pragma unroll
    for (int ks = 0; ks < 4; ++ks) {
      bf16x8 k0 = *(const bf16x8*)(kp0 + ks * 16);
      bf16x8 k1 = *(const bf16x8*)(kp0 + 32 * ODIM_ + ks * 16);
      s0 = __builtin_amdgcn_mfma_f32_32x32x16_bf16(k0, qf[ks], s0, 0, 0, 0);
      s1 = __builtin_amdgcn_mfma_f32_32x32x16_bf16(k1, qf[ks], s1, 0, 0, 0);
    }

    // ---- mask multipliers; reg r -> kv = (r<8 ? 8*hi+r : 8+8*hi+r) (+32 s1)
    f32x4 mq0[4], mq1[4];
    mq0[0] = *(const f32x4*)(mp + 0);
    mq0[1] = *(const f32x4*)(mp + 4);
    mq0[2] = *(const f32x4*)(mp + 16);
    mq0[3] = *(const f32x4*)(mp + 20);
    mq1[0] = *(const f32x4*)(mp + 32);
    mq1[1] = *(const f32x4*)(mp + 36);
    mq1[2] = *(const f32x4*)(mp + 48);
    mq1[3] = *(const f32x4*)(mp + 52);

    // ---- row max over all 64 kv of this tile (order-agnostic)
    float rm = s0[0];
#pragma unroll
    for (int r = 1; r < 16; ++r) rm = fmaxf(rm, s0[r]);
#pragma unroll
    for (int r = 0; r < 16; ++r) rm = fmaxf(rm, s1[r]);
    rm = fmaxf(rm, __shfl_xor(rm, 32));
    const float pm = rm * csc;

    // ---- defer-max rescale (rare; wave-uniform branch)
    if (__any(pm > m_ + 11.0f)) {
      const float mn = fmaxf(m_, pm);
      const float alpha = fast_exp2(m_ - mn);
      l_ *= alpha;
      m_ = mn;
#pragma unroll
      for (int r = 0; r < 16; ++r) {
        const float av = __shfl(alpha, (r & 3) + 8 * (r >> 2) + 4 * hi);
        oacc0[r] *= av;
        oacc1[r] *= av;
      }
    }

    // ---- p = 2^(s*c - m) * mask ; row sum
    float psum = 0.f;
#pragma unroll
    for (int r = 0; r < 16; ++r) {
      float p0 = fast_exp2(fmaf(s0[r], csc, -m_)) * mq0[r >> 2][r & 3];
      float p1 = fast_exp2(fmaf(s1[r], csc, -m_)) * mq1[r >> 2][r & 3];
      s0[r] = p0;
      s1[r] = p1;
      psum += p0 + p1;
    }
    psum += __shfl_xor(psum, 32);
    l_ += psum;

    // ---- pack P into PV A-frags: pure lane-local cvt_pk (no cross-lane!)
    bf16x8 pa[4];
    pa[0] = make_frag(cvtpk(s0[0], s0[1]), cvtpk(s0[2], s0[3]),
                      cvtpk(s0[4], s0[5]), cvtpk(s0[6], s0[7]));
    pa[1] = make_frag(cvtpk(s0[8], s0[9]), cvtpk(s0[10], s0[11]),
                      cvtpk(s0[12], s0[13]), cvtpk(s0[14], s0[15]));
    pa[2] = make_frag(cvtpk(s1[0], s1[1]), cvtpk(s1[2], s1[3]),
                      cvtpk(s1[4], s1[5]), cvtpk(s1[6], s1[7]));
    pa[3] = make_frag(cvtpk(s1[8], s1[9]), cvtpk(s1[10], s1[11]),
                      cvtpk(s1[12], s1[13]), cvtpk(s1[14], s1[15]));

    // ---- O += P @ V (V consumed in natural kv order; matches pa by design)
#pragma unroll
    for (int ks = 0; ks < 4; ++ks) {
      bf16x8 v0 = *(const bf16x8*)(vp0 + ks * 16);
      bf16x8 v1 = *(const bf16x8*)(vp0 + 32 * LKV_ + ks * 16);
      oacc0 = __builtin_amdgcn_mfma_f32_32x32x16_bf16(pa[ks], v0, oacc0, 0, 0, 0);
      oacc1 = __builtin_amdgcn_mfma_f32_32x32x16_bf16(pa[ks], v1, oacc1, 0, 0, 0);
    }

    kp0 += 64 * ODIM_;
    vp0 += 64;
    mp += 64;
  }

  // ---- epilogue: O /= l ; store bf16
  const float linv = 1.0f / l_;
  const size_t obase = (size_t)(b * LQ_ + q0) * ODIM_ + h * HD_;
#pragma unroll
  for (int r = 0; r < 16; ++r) {
    const int cr = (r & 3) + 8 * (r >> 2) + 4 * hi;
    const float lv = __shfl(linv, cr);
    att[obase + (size_t)cr * ODIM_ + l31] = __float2bfloat16(oacc0[r] * lv);
    att[obase + (size_t)cr * ODIM_ + 32 + l31] = __float2bfloat16(oacc1[r] * lv);
  }
}

// ---------------------------------------------------------------------------
extern "C" void kernel_launch(void* const* d_in, const int* in_sizes, int n_in,
                              void* d_out, int out_size, void* d_ws,
                              size_t ws_size, hipStream_t stream) {
  const float* query = (const float*)d_in[0];
  const float* key   = (const float*)d_in[1];
  const float* value = (const float*)d_in[2];
  const void* mask_raw = d_in[3];
  const float* Wq = (const float*)d_in[4];
  const float* bq = (const float*)d_in[5];
  const float* Wk = (const float*)d_in[6];
  const float* bk = (const float*)d_in[7];
  const float* Wv = (const float*)d_in[8];
  const float* bv = (const float*)d_in[9];
  const float* Wo = (const float*)d_in[10];
  const float* bo = (const float*)d_in[11];
  float* out = (float*)d_out;

  char* ws = (char*)d_ws;
  bf16* qb  = (bf16*)(ws + 0);          // 4096x1024   [0, 8388608)
  bf16* att = qb;                       // alias (qb dead after gemm-Q)
  bf16* kb  = (bf16*)(ws + 8388608);    // 8192x768
  bf16* vb  = (bf16*)(ws + 20971520);   // 8192x768
  bf16* vT  = (bf16*)(ws + 16777216);   // [B][H][64][2048] alias over kb tail
  bf16* WqT = (bf16*)(ws + 33554432);
  bf16* WkT = (bf16*)(ws + 35651584);
  bf16* WvT = (bf16*)(ws + 37224448);
  bf16* WoT = (bf16*)(ws + 38797312);
  bf16* qp  = (bf16*)(ws + 40894464);
  bf16* kp  = (bf16*)(ws + 49283072);
  bf16* vp  = (bf16*)(ws + 66060288);
  float* mf = (float*)(ws + 82837504);  // 8192 floats

  mask_prep<<<1, 256, 0, stream>>>(mask_raw, mf, B_ * LKV_);

  cvt_f32_to_bf16<<<4096, 256, 0, stream>>>(query, qb, (B_ * LQ_ * QDIM_) / 4);
  cvt_f32_to_bf16<<<6144, 256, 0, stream>>>(key, kb, (B_ * LKV_ * KDIM_) / 4);
  cvt_f32_to_bf16<<<6144, 256, 0, stream>>>(value, vb, (B_ * LKV_ * KDIM_) / 4);

  wtrans<<<dim3(16, 16), 256, 0, stream>>>(Wq, WqT, QDIM_, ODIM_);
  wtrans<<<dim3(16, 12), 256, 0, stream>>>(Wk, WkT, KDIM_, ODIM_);
  wtrans<<<dim3(16, 12), 256, 0, stream>>>(Wv, WvT, KDIM_, ODIM_);
  wtrans<<<dim3(16, 16), 256, 0, stream>>>(Wo, WoT, ODIM_, ODIM_);

  gemm_bt<1><<<dim3(8, 32), 256, 0, stream>>>(qb, WqT, bq, qp,
                                              B_ * LQ_, ODIM_, QDIM_);
  gemm_bt<1><<<dim3(8, 64), 256, 0, stream>>>(kb, WkT, bk, kp,
                                              B_ * LKV_, ODIM_, KDIM_);
  gemm_bt<1><<<dim3(8, 64), 256, 0, stream>>>(vb, WvT, bv, vp,
                                              B_ * LKV_, ODIM_, KDIM_);

  vtrans<<<dim3(32, 16, 4), 256, 0, stream>>>(vp, vT);

  attn3<<<512, 256, 0, stream>>>(qp, kp, vT, mf, att);

  gemm_bt<0><<<dim3(8, 32), 256, 0, stream>>>(att, WoT, bo, out,
                                              B_ * LQ_, ODIM_, ODIM_);
}

// Round 6
// 386.248 us; speedup vs baseline: 1.0373x; 1.0373x over previous
//
#include <hip/hip_runtime.h>
#include <hip/hip_bf16.h>
#include <cstdint>
#include <cstddef>

using bf16 = __hip_bfloat16;
typedef __attribute__((ext_vector_type(8))) short bf16x8;   // 8 bf16 (MFMA A/B frag)
typedef __attribute__((ext_vector_type(4))) float f32x4;    // 16x16 MFMA C/D frag
typedef __attribute__((ext_vector_type(16))) float f32x16;  // 32x32 MFMA C/D frag

#define B_    4
#define LQ_   1024
#define LKV_  2048
#define QDIM_ 1024
#define KDIM_ 768
#define ODIM_ 1024
#define H_    16
#define HD_   64

// ---------------------------------------------------------------------------
// async global -> LDS, 16B per lane (wave-uniform LDS base + lane*16)
// ---------------------------------------------------------------------------
__device__ __forceinline__ void async_cp16(const void* g, void* l) {
  __builtin_amdgcn_global_load_lds(
      (const __attribute__((address_space(1))) void*)g,
      (__attribute__((address_space(3))) void*)l, 16, 0, 0);
}

// pack two f32 -> one u32 of 2 bf16 (lo = a, hi = b)
__device__ __forceinline__ unsigned cvtpk(float a, float b) {
  unsigned r;
  asm("v_cvt_pk_bf16_f32 %0, %1, %2" : "=v"(r) : "v"(a), "v"(b));
  return r;
}

__device__ __forceinline__ float fast_exp2(float x) {
#if __has_builtin(__builtin_amdgcn_exp2f)
  return __builtin_amdgcn_exp2f(x);
#else
  return exp2f(x);
#endif
}

__device__ __forceinline__ bf16x8 make_frag(unsigned w0, unsigned w1,
                                            unsigned w2, unsigned w3) {
  union { unsigned u[4]; bf16x8 v; } u;
  u.u[0] = w0; u.u[1] = w1; u.u[2] = w2; u.u[3] = w3;
  return u.v;
}

// ---------------------------------------------------------------------------
// mask normalize (parallel): input may be 1-byte bools or int32 0/1; emit
// float 1.0=keep, 0.0=masked. Every block independently re-derives the format
// (scan is 8KB, cheap) so no cross-block communication is needed.
// ---------------------------------------------------------------------------
__global__ void mask_prep(const void* __restrict__ mraw,
                          float* __restrict__ mf, int n) {
  const int tid = threadIdx.x;
  const unsigned char* bb = (const unsigned char*)mraw;
  int local = 0;
  for (int i = tid; i < n; i += 256)
    if ((i & 3) != 0 && bb[i] != 0) local = 1;
  __shared__ int f;
  if (tid == 0) f = 0;
  __syncthreads();
  if (__any(local) && (tid & 63) == 0) atomicOr(&f, 1);
  __syncthreads();
  const int is8 = f;
  const int* w = (const int*)mraw;
  for (int i = blockIdx.x * 256 + tid; i < n; i += gridDim.x * 256)
    mf[i] = (is8 ? (int)bb[i] : (w[i] != 0)) ? 0.f : 1.f;
}

// ---------------------------------------------------------------------------
// fp32 -> bf16 elementwise convert
// ---------------------------------------------------------------------------
struct alignas(8) bf4 { bf16 x[4]; };

__global__ void cvt_f32_to_bf16(const float* __restrict__ in,
                                bf16* __restrict__ out, int n4) {
  int i = blockIdx.x * blockDim.x + threadIdx.x;
  if (i >= n4) return;
  float4 v = reinterpret_cast<const float4*>(in)[i];
  bf4 r;
  r.x[0] = __float2bfloat16(v.x);
  r.x[1] = __float2bfloat16(v.y);
  r.x[2] = __float2bfloat16(v.z);
  r.x[3] = __float2bfloat16(v.w);
  *reinterpret_cast<bf4*>(out + (size_t)i * 4) = r;
}

// ---------------------------------------------------------------------------
// weight transpose + convert: W [K][N] fp32  ->  WT [N][K] bf16
// ---------------------------------------------------------------------------
__global__ void wtrans(const float* __restrict__ W, bf16* __restrict__ WT,
                       int K, int N) {
  __shared__ bf16 t[64][65];
  const int n0 = blockIdx.x * 64, k0 = blockIdx.y * 64;
  const int tid = threadIdx.x;
#pragma unroll
  for (int i = 0; i < 16; ++i) {
    int idx = tid + i * 256;
    int nn = idx & 63, kk = idx >> 6;
    t[kk][nn] = __float2bfloat16(W[(size_t)(k0 + kk) * N + n0 + nn]);
  }
  __syncthreads();
#pragma unroll
  for (int i = 0; i < 16; ++i) {
    int idx = tid + i * 256;
    int kk = idx & 63, nn = idx >> 6;
    WT[(size_t)(n0 + nn) * K + k0 + kk] = t[kk][nn];
  }
}

// ---------------------------------------------------------------------------
// V transpose: vp [B][LKV][ODIM] bf16 -> vT [B][H][HD][LKV] bf16
// ---------------------------------------------------------------------------
__global__ void vtrans(const bf16* __restrict__ vp, bf16* __restrict__ vT) {
  __shared__ bf16 t[64][65];
  const int kv0 = blockIdx.x * 64, h = blockIdx.y, b = blockIdx.z;
  const int tid = threadIdx.x;
#pragma unroll
  for (int i = 0; i < 16; ++i) {
    int idx = tid + i * 256;
    int hd = idx & 63, kv = idx >> 6;
    t[kv][hd] = vp[(size_t)(b * LKV_ + kv0 + kv) * ODIM_ + h * HD_ + hd];
  }
  __syncthreads();
#pragma unroll
  for (int i = 0; i < 16; ++i) {
    int idx = tid + i * 256;
    int kv = idx & 63, nn = idx >> 6;
    vT[(size_t)((b * H_ + h) * HD_ + nn) * LKV_ + kv0 + kv] = t[kv][nn];
  }
}

// ---------------------------------------------------------------------------
// GEMM: C[M][N] = A[M][K] @ BT[N][K]^T + bias  (unchanged)
// ---------------------------------------------------------------------------
template <int OUT_BF16>
__launch_bounds__(256, 2)
__global__ void gemm_bt(const bf16* __restrict__ A, const bf16* __restrict__ BT,
                        const float* __restrict__ bias, void* __restrict__ Cout,
                        int M, int N, int K) {
  __shared__ bf16 As[128 * 64];
  __shared__ bf16 Bs[128 * 64];
  const int tid = threadIdx.x;
  const int lane = tid & 63, w = tid >> 6;
  const int wr = w >> 1, wc = w & 1;
  const int lr = lane & 15, lk = lane >> 4;
  const int m0 = blockIdx.y * 128, n0 = blockIdx.x * 128;

  f32x4 acc[4][4];
#pragma unroll
  for (int m = 0; m < 4; ++m)
#pragma unroll
    for (int n = 0; n < 4; ++n) acc[m][n] = (f32x4){0.f, 0.f, 0.f, 0.f};

  const int nk = K >> 6;
  for (int kt = 0; kt < nk; ++kt) {
    const int k0 = kt << 6;
#pragma unroll
    for (int i = 0; i < 4; ++i) {
      const int c = tid + i * 256;
      const int row = c >> 3, cc = c & 7;
      const int sc = cc ^ (row & 7);
      async_cp16(A + (size_t)(m0 + row) * K + k0 + sc * 8, As + c * 8);
    }
#pragma unroll
    for (int i = 0; i < 4; ++i) {
      const int c = tid + i * 256;
      const int row = c >> 3, cc = c & 7;
      const int sc = cc ^ (row & 7);
      async_cp16(BT + (size_t)(n0 + row) * K + k0 + sc * 8, Bs + c * 8);
    }
    asm volatile("s_waitcnt vmcnt(0)" ::: "memory");
    __syncthreads();

    bf16x8 af[4][2], bfr[4][2];
#pragma unroll
    for (int m = 0; m < 4; ++m)
#pragma unroll
      for (int ks = 0; ks < 2; ++ks) {
        const int r = wr * 64 + m * 16 + lr;
        af[m][ks] = *(const bf16x8*)((const char*)As + r * 128 +
                                     ((ks * 64 + lk * 16) ^ ((r & 7) << 4)));
      }
#pragma unroll
    for (int n = 0; n < 4; ++n)
#pragma unroll
      for (int ks = 0; ks < 2; ++ks) {
        const int r = wc * 64 + n * 16 + lr;
        bfr[n][ks] = *(const bf16x8*)((const char*)Bs + r * 128 +
                                      ((ks * 64 + lk * 16) ^ ((r & 7) << 4)));
      }
#pragma unroll
    for (int m = 0; m < 4; ++m)
#pragma unroll
      for (int n = 0; n < 4; ++n)
#pragma unroll
        for (int ks = 0; ks < 2; ++ks)
          acc[m][n] = __builtin_amdgcn_mfma_f32_16x16x32_bf16(
              af[m][ks], bfr[n][ks], acc[m][n], 0, 0, 0);
    __syncthreads();
  }

#pragma unroll
  for (int m = 0; m < 4; ++m)
#pragma unroll
    for (int n = 0; n < 4; ++n)
#pragma unroll
      for (int r4 = 0; r4 < 4; ++r4) {
        const int row = m0 + wr * 64 + m * 16 + lk * 4 + r4;
        const int col = n0 + wc * 64 + n * 16 + lr;
        float v = acc[m][n][r4] + bias[col];
        if (OUT_BF16)
          ((bf16*)Cout)[(size_t)row * N + col] = __float2bfloat16(v);
        else
          ((float*)Cout)[(size_t)row * N + col] = v;
      }
}

// ---------------------------------------------------------------------------
// Flash attention v4: v3 (sigma-permuted K rows, in-register softmax, zero
// LDS/barriers) + REGISTER DOUBLE-BUFFERED K/V PREFETCH. The kv loop is
// unrolled by 2 with A/B register sets; tile t+1's 16 global loads are issued
// before tile t's compute, hiding ~L2 latency under MFMA+softmax.
// Grid: 512 blocks, d%8 = XCD; 8 (b,h) pairs per XCD -> K/V set = 4MB = L2.
// ---------------------------------------------------------------------------
__launch_bounds__(256, 2)
__global__ void attn4(const bf16* __restrict__ qp, const bf16* __restrict__ kp,
                      const bf16* __restrict__ vT, const float* __restrict__ mf,
                      bf16* __restrict__ att) {
  const int tid = threadIdx.x;
  const int w = tid >> 6, l = tid & 63;
  const int l31 = l & 31, hi = l >> 5;
  const int d = blockIdx.x;
  const int hb = (d & 7) * 8 + ((d >> 3) & 7);  // XCD-chunked (b,h)
  const int qt = d >> 6;
  const int h = hb & 15, b = hb >> 4;
  const int q0 = qt * 128 + w * 32;

  // sigma: A-row m (=l31) loads physical K row sigma(m)
  const int rr = (l31 & 3) + 4 * (l31 >> 3);
  const int hh = (l31 >> 2) & 1;
  const int sig = (rr < 8) ? (8 * hh + rr) : (8 + 8 * hh + rr);

  // Q fragments (B-operand): lane holds Q[q0+l31][hd = ks*16 + hi*8 + j]
  bf16x8 qf[4];
  {
    const bf16* qb =
        qp + (size_t)(b * LQ_ + q0 + l31) * ODIM_ + h * HD_ + hi * 8;
#pragma unroll
    for (int ks = 0; ks < 4; ++ks) qf[ks] = *(const bf16x8*)(qb + ks * 16);
  }
  const bf16* kpb = kp + (size_t)(b * LKV_ + sig) * ODIM_ + h * HD_ + hi * 8;
  const bf16* vpb = vT + (size_t)((b * H_ + h) * HD_ + l31) * LKV_ + hi * 8;
  const float* mpb = mf + b * LKV_ + hi * 8;

  f32x16 oacc0, oacc1;
#pragma unroll
  for (int r = 0; r < 16; ++r) { oacc0[r] = 0.f; oacc1[r] = 0.f; }
  float m_ = -1e30f, l_ = 0.f;
  const float csc = 0.125f * 1.4426950408889634f;  // scale * log2(e)

  // KR[0..3] = kv sub-block 0 (rows sig), KR[4..7] = sub-block 1 (rows sig+32)
  // VR[0..3] = hd row l31,              VR[4..7] = hd row l31+32
  auto loadt = [&](bf16x8 (&KR)[8], bf16x8 (&VR)[8], int t) {
    const bf16* kt = kpb + (size_t)t * (64 * ODIM_);
    const bf16* vt = vpb + t * 64;
#pragma unroll
    for (int ks = 0; ks < 4; ++ks) {
      KR[ks] = *(const bf16x8*)(kt + ks * 16);
      KR[4 + ks] = *(const bf16x8*)(kt + 32 * ODIM_ + ks * 16);
      VR[ks] = *(const bf16x8*)(vt + ks * 16);
      VR[4 + ks] = *(const bf16x8*)(vt + 32 * LKV_ + ks * 16);
    }
  };

  auto compute = [&](const bf16x8 (&KR)[8], const bf16x8 (&VR)[8], int t) {
    // mask multipliers issued first (needed only after the QK MFMAs)
    const float* mt = mpb + t * 64;
    f32x4 mq0[4], mq1[4];
    mq0[0] = *(const f32x4*)(mt + 0);
    mq0[1] = *(const f32x4*)(mt + 4);
    mq0[2] = *(const f32x4*)(mt + 16);
    mq0[3] = *(const f32x4*)(mt + 20);
    mq1[0] = *(const f32x4*)(mt + 32);
    mq1[1] = *(const f32x4*)(mt + 36);
    mq1[2] = *(const f32x4*)(mt + 48);
    mq1[3] = *(const f32x4*)(mt + 52);

    f32x16 s0, s1;
#pragma unroll
    for (int r = 0; r < 16; ++r) { s0[r] = 0.f; s1[r] = 0.f; }
#pragma unroll
    for (int ks = 0; ks < 4; ++ks) {
      s0 = __builtin_amdgcn_mfma_f32_32x32x16_bf16(KR[ks], qf[ks], s0, 0, 0, 0);
      s1 = __builtin_amdgcn_mfma_f32_32x32x16_bf16(KR[4 + ks], qf[ks], s1, 0, 0, 0);
    }

    // row max over all 64 kv of this tile (order-agnostic)
    float rm = s0[0];
#pragma unroll
    for (int r = 1; r < 16; ++r) rm = fmaxf(rm, s0[r]);
#pragma unroll
    for (int r = 0; r < 16; ++r) rm = fmaxf(rm, s1[r]);
    rm = fmaxf(rm, __shfl_xor(rm, 32));
    const float pm = rm * csc;

    // defer-max rescale (rare; wave-uniform branch)
    if (__any(pm > m_ + 11.0f)) {
      const float mn = fmaxf(m_, pm);
      const float alpha = fast_exp2(m_ - mn);
      l_ *= alpha;
      m_ = mn;
#pragma unroll
      for (int r = 0; r < 16; ++r) {
        const float av = __shfl(alpha, (r & 3) + 8 * (r >> 2) + 4 * hi);
        oacc0[r] *= av;
        oacc1[r] *= av;
      }
    }

    // p = 2^(s*c - m) * mask ; row sum
    float psum = 0.f;
#pragma unroll
    for (int r = 0; r < 16; ++r) {
      float p0 = fast_exp2(fmaf(s0[r], csc, -m_)) * mq0[r >> 2][r & 3];
      float p1 = fast_exp2(fmaf(s1[r], csc, -m_)) * mq1[r >> 2][r & 3];
      s0[r] = p0;
      s1[r] = p1;
      psum += p0 + p1;
    }
    psum += __shfl_xor(psum, 32);
    l_ += psum;

    // pack P into PV A-frags: pure lane-local cvt_pk
    bf16x8 pa[4];
    pa[0] = make_frag(cvtpk(s0[0], s0[1]), cvtpk(s0[2], s0[3]),
                      cvtpk(s0[4], s0[5]), cvtpk(s0[6], s0[7]));
    pa[1] = make_frag(cvtpk(s0[8], s0[9]), cvtpk(s0[10], s0[11]),
                      cvtpk(s0[12], s0[13]), cvtpk(s0[14], s0[15]));
    pa[2] = make_frag(cvtpk(s1[0], s1[1]), cvtpk(s1[2], s1[3]),
                      cvtpk(s1[4], s1[5]), cvtpk(s1[6], s1[7]));
    pa[3] = make_frag(cvtpk(s1[8], s1[9]), cvtpk(s1[10], s1[11]),
                      cvtpk(s1[12], s1[13]), cvtpk(s1[14], s1[15]));

    // O += P @ V
#pragma unroll
    for (int ks = 0; ks < 4; ++ks) {
      oacc0 = __builtin_amdgcn_mfma_f32_32x32x16_bf16(pa[ks], VR[ks], oacc0, 0, 0, 0);
      oacc1 = __builtin_amdgcn_mfma_f32_32x32x16_bf16(pa[ks], VR[4 + ks], oacc1, 0, 0, 0);
    }
  };

  // software pipeline: unroll-2, A/B register double-buffer
  bf16x8 kA[8], vA[8], kB[8], vB[8];
  loadt(kA, vA, 0);
  const int NT = LKV_ / 64;  // 32
  for (int t = 0; t < NT; t += 2) {
    loadt(kB, vB, t + 1);
    compute(kA, vA, t);
    loadt(kA, vA, (t + 2) & (NT - 1));  // wraps to 0 on last iter (harmless)
    compute(kB, vB, t + 1);
  }

  // epilogue: O /= l ; store bf16
  const float linv = 1.0f / l_;
  const size_t obase = (size_t)(b * LQ_ + q0) * ODIM_ + h * HD_;
#pragma unroll
  for (int r = 0; r < 16; ++r) {
    const int cr = (r & 3) + 8 * (r >> 2) + 4 * hi;
    const float lv = __shfl(linv, cr);
    att[obase + (size_t)cr * ODIM_ + l31] = __float2bfloat16(oacc0[r] * lv);
    att[obase + (size_t)cr * ODIM_ + 32 + l31] = __float2bfloat16(oacc1[r] * lv);
  }
}

// ---------------------------------------------------------------------------
extern "C" void kernel_launch(void* const* d_in, const int* in_sizes, int n_in,
                              void* d_out, int out_size, void* d_ws,
                              size_t ws_size, hipStream_t stream) {
  const float* query = (const float*)d_in[0];
  const float* key   = (const float*)d_in[1];
  const float* value = (const float*)d_in[2];
  const void* mask_raw = d_in[3];
  const float* Wq = (const float*)d_in[4];
  const float* bq = (const float*)d_in[5];
  const float* Wk = (const float*)d_in[6];
  const float* bk = (const float*)d_in[7];
  const float* Wv = (const float*)d_in[8];
  const float* bv = (const float*)d_in[9];
  const float* Wo = (const float*)d_in[10];
  const float* bo = (const float*)d_in[11];
  float* out = (float*)d_out;

  char* ws = (char*)d_ws;
  bf16* qb  = (bf16*)(ws + 0);          // 4096x1024   [0, 8388608)
  bf16* att = qb;                       // alias (qb dead after gemm-Q)
  bf16* kb  = (bf16*)(ws + 8388608);    // 8192x768
  bf16* vb  = (bf16*)(ws + 20971520);   // 8192x768
  bf16* vT  = (bf16*)(ws + 16777216);   // [B][H][64][2048] alias over kb tail
  bf16* WqT = (bf16*)(ws + 33554432);
  bf16* WkT = (bf16*)(ws + 35651584);
  bf16* WvT = (bf16*)(ws + 37224448);
  bf16* WoT = (bf16*)(ws + 38797312);
  bf16* qp  = (bf16*)(ws + 40894464);
  bf16* kp  = (bf16*)(ws + 49283072);
  bf16* vp  = (bf16*)(ws + 66060288);
  float* mf = (float*)(ws + 82837504);  // 8192 floats

  mask_prep<<<32, 256, 0, stream>>>(mask_raw, mf, B_ * LKV_);

  cvt_f32_to_bf16<<<4096, 256, 0, stream>>>(query, qb, (B_ * LQ_ * QDIM_) / 4);
  cvt_f32_to_bf16<<<6144, 256, 0, stream>>>(key, kb, (B_ * LKV_ * KDIM_) / 4);
  cvt_f32_to_bf16<<<6144, 256, 0, stream>>>(value, vb, (B_ * LKV_ * KDIM_) / 4);

  wtrans<<<dim3(16, 16), 256, 0, stream>>>(Wq, WqT, QDIM_, ODIM_);
  wtrans<<<dim3(16, 12), 256, 0, stream>>>(Wk, WkT, KDIM_, ODIM_);
  wtrans<<<dim3(16, 12), 256, 0, stream>>>(Wv, WvT, KDIM_, ODIM_);
  wtrans<<<dim3(16, 16), 256, 0, stream>>>(Wo, WoT, ODIM_, ODIM_);

  gemm_bt<1><<<dim3(8, 32), 256, 0, stream>>>(qb, WqT, bq, qp,
                                              B_ * LQ_, ODIM_, QDIM_);
  gemm_bt<1><<<dim3(8, 64), 256, 0, stream>>>(kb, WkT, bk, kp,
                                              B_ * LKV_, ODIM_, KDIM_);
  gemm_bt<1><<<dim3(8, 64), 256, 0, stream>>>(vb, WvT, bv, vp,
                                              B_ * LKV_, ODIM_, KDIM_);

  vtrans<<<dim3(32, 16, 4), 256, 0, stream>>>(vp, vT);

  attn4<<<512, 256, 0, stream>>>(qp, kp, vT, mf, att);

  gemm_bt<0><<<dim3(8, 32), 256, 0, stream>>>(att, WoT, bo, out,
                                              B_ * LQ_, ODIM_, ODIM_);
}

// Round 7
// 282.185 us; speedup vs baseline: 1.4198x; 1.3688x over previous
//
#include <hip/hip_runtime.h>
#include <hip/hip_bf16.h>
#include <cstdint>
#include <cstddef>

using bf16 = __hip_bfloat16;
typedef __attribute__((ext_vector_type(8))) short bf16x8;   // 8 bf16 (MFMA A/B frag)
typedef __attribute__((ext_vector_type(4))) float f32x4;    // 16x16 MFMA C/D frag
typedef __attribute__((ext_vector_type(16))) float f32x16;  // 32x32 MFMA C/D frag

#define B_    4
#define LQ_   1024
#define LKV_  2048
#define QDIM_ 1024
#define KDIM_ 768
#define ODIM_ 1024
#define H_    16
#define HD_   64

// ---------------------------------------------------------------------------
// async global -> LDS, 16B per lane (wave-uniform LDS base + lane*16)
// ---------------------------------------------------------------------------
__device__ __forceinline__ void async_cp16(const void* g, void* l) {
  __builtin_amdgcn_global_load_lds(
      (const __attribute__((address_space(1))) void*)g,
      (__attribute__((address_space(3))) void*)l, 16, 0, 0);
}

// pack two f32 -> one u32 of 2 bf16 (lo = a, hi = b)
__device__ __forceinline__ unsigned cvtpk(float a, float b) {
  unsigned r;
  asm("v_cvt_pk_bf16_f32 %0, %1, %2" : "=v"(r) : "v"(a), "v"(b));
  return r;
}

__device__ __forceinline__ float fast_exp2(float x) {
#if __has_builtin(__builtin_amdgcn_exp2f)
  return __builtin_amdgcn_exp2f(x);
#else
  return exp2f(x);
#endif
}

__device__ __forceinline__ bf16x8 make_frag(unsigned w0, unsigned w1,
                                            unsigned w2, unsigned w3) {
  union { unsigned u[4]; bf16x8 v; } u;
  u.u[0] = w0; u.u[1] = w1; u.u[2] = w2; u.u[3] = w3;
  return u.v;
}

// ---------------------------------------------------------------------------
// mask normalize (parallel): 1-byte bool or int32 0/1 -> float 1.0=keep/0.0=mask
// ---------------------------------------------------------------------------
__global__ void mask_prep(const void* __restrict__ mraw,
                          float* __restrict__ mf, int n) {
  const int tid = threadIdx.x;
  const unsigned char* bb = (const unsigned char*)mraw;
  int local = 0;
  for (int i = tid; i < n; i += 256)
    if ((i & 3) != 0 && bb[i] != 0) local = 1;
  __shared__ int f;
  if (tid == 0) f = 0;
  __syncthreads();
  if (__any(local) && (tid & 63) == 0) atomicOr(&f, 1);
  __syncthreads();
  const int is8 = f;
  const int* w = (const int*)mraw;
  for (int i = blockIdx.x * 256 + tid; i < n; i += gridDim.x * 256)
    mf[i] = (is8 ? (int)bb[i] : (w[i] != 0)) ? 0.f : 1.f;
}

// ---------------------------------------------------------------------------
// fused fp32 -> bf16 convert for query/key/value (blockIdx.y selects tensor)
// ---------------------------------------------------------------------------
struct alignas(8) bf4 { bf16 x[4]; };

__global__ void cvt3(const float* __restrict__ q, const float* __restrict__ k,
                     const float* __restrict__ v, bf16* __restrict__ qb,
                     bf16* __restrict__ kb, bf16* __restrict__ vb) {
  const int z = blockIdx.y;
  const float* src = (z == 0) ? q : (z == 1) ? k : v;
  bf16* dst = (z == 0) ? qb : (z == 1) ? kb : vb;
  const int n4 = (z == 0) ? (B_ * LQ_ * QDIM_) / 4 : (B_ * LKV_ * KDIM_) / 4;
  const int i = blockIdx.x * 256 + threadIdx.x;
  if (i >= n4) return;
  float4 val = reinterpret_cast<const float4*>(src)[i];
  bf4 r;
  r.x[0] = __float2bfloat16(val.x);
  r.x[1] = __float2bfloat16(val.y);
  r.x[2] = __float2bfloat16(val.z);
  r.x[3] = __float2bfloat16(val.w);
  *reinterpret_cast<bf4*>(dst + (size_t)i * 4) = r;
}

// ---------------------------------------------------------------------------
// fused weight transpose + convert: W [K][1024] fp32 -> WT [1024][K] bf16, z=4
// ---------------------------------------------------------------------------
__global__ void wtrans4(const float* __restrict__ Wq, const float* __restrict__ Wk,
                        const float* __restrict__ Wv, const float* __restrict__ Wo,
                        bf16* __restrict__ WqT, bf16* __restrict__ WkT,
                        bf16* __restrict__ WvT, bf16* __restrict__ WoT) {
  const int z = blockIdx.z;
  const float* W = (z == 0) ? Wq : (z == 1) ? Wk : (z == 2) ? Wv : Wo;
  bf16* WT = (z == 0) ? WqT : (z == 1) ? WkT : (z == 2) ? WvT : WoT;
  const int K = (z == 1 || z == 2) ? KDIM_ : ODIM_;
  const int N = ODIM_;
  const int n0 = blockIdx.x * 64, k0 = blockIdx.y * 64;
  if (k0 >= K) return;
  __shared__ bf16 t[64][65];
  const int tid = threadIdx.x;
#pragma unroll
  for (int i = 0; i < 16; ++i) {
    int idx = tid + i * 256;
    int nn = idx & 63, kk = idx >> 6;
    t[kk][nn] = __float2bfloat16(W[(size_t)(k0 + kk) * N + n0 + nn]);
  }
  __syncthreads();
#pragma unroll
  for (int i = 0; i < 16; ++i) {
    int idx = tid + i * 256;
    int kk = idx & 63, nn = idx >> 6;
    WT[(size_t)(n0 + nn) * K + k0 + kk] = t[kk][nn];
  }
}

// ---------------------------------------------------------------------------
// V transpose: vp [B][LKV][ODIM] bf16 -> vT [B][H][HD][LKV] bf16
// ---------------------------------------------------------------------------
__global__ void vtrans(const bf16* __restrict__ vp, bf16* __restrict__ vT) {
  __shared__ bf16 t[64][65];
  const int kv0 = blockIdx.x * 64, h = blockIdx.y, b = blockIdx.z;
  const int tid = threadIdx.x;
#pragma unroll
  for (int i = 0; i < 16; ++i) {
    int idx = tid + i * 256;
    int hd = idx & 63, kv = idx >> 6;
    t[kv][hd] = vp[(size_t)(b * LKV_ + kv0 + kv) * ODIM_ + h * HD_ + hd];
  }
  __syncthreads();
#pragma unroll
  for (int i = 0; i < 16; ++i) {
    int idx = tid + i * 256;
    int kv = idx & 63, nn = idx >> 6;
    vT[(size_t)((b * H_ + h) * HD_ + nn) * LKV_ + kv0 + kv] = t[kv][nn];
  }
}

// ---------------------------------------------------------------------------
// GEMM body: C[M][N] = A[M][K] @ BT[N][K]^T + bias (m97 structure)
// ---------------------------------------------------------------------------
template <int OUT_BF16>
__device__ __forceinline__ void gemm_body(const bf16* __restrict__ A,
                                          const bf16* __restrict__ BT,
                                          const float* __restrict__ bias,
                                          void* __restrict__ Cout,
                                          int M, int N, int K, int m0, int n0) {
  __shared__ bf16 As[128 * 64];
  __shared__ bf16 Bs[128 * 64];
  const int tid = threadIdx.x;
  const int lane = tid & 63, w = tid >> 6;
  const int wr = w >> 1, wc = w & 1;
  const int lr = lane & 15, lk = lane >> 4;

  f32x4 acc[4][4];
#pragma unroll
  for (int m = 0; m < 4; ++m)
#pragma unroll
    for (int n = 0; n < 4; ++n) acc[m][n] = (f32x4){0.f, 0.f, 0.f, 0.f};

  const int nk = K >> 6;
  for (int kt = 0; kt < nk; ++kt) {
    const int k0 = kt << 6;
#pragma unroll
    for (int i = 0; i < 4; ++i) {
      const int c = tid + i * 256;
      const int row = c >> 3, cc = c & 7;
      const int sc = cc ^ (row & 7);
      async_cp16(A + (size_t)(m0 + row) * K + k0 + sc * 8, As + c * 8);
    }
#pragma unroll
    for (int i = 0; i < 4; ++i) {
      const int c = tid + i * 256;
      const int row = c >> 3, cc = c & 7;
      const int sc = cc ^ (row & 7);
      async_cp16(BT + (size_t)(n0 + row) * K + k0 + sc * 8, Bs + c * 8);
    }
    asm volatile("s_waitcnt vmcnt(0)" ::: "memory");
    __syncthreads();

    bf16x8 af[4][2], bfr[4][2];
#pragma unroll
    for (int m = 0; m < 4; ++m)
#pragma unroll
      for (int ks = 0; ks < 2; ++ks) {
        const int r = wr * 64 + m * 16 + lr;
        af[m][ks] = *(const bf16x8*)((const char*)As + r * 128 +
                                     ((ks * 64 + lk * 16) ^ ((r & 7) << 4)));
      }
#pragma unroll
    for (int n = 0; n < 4; ++n)
#pragma unroll
      for (int ks = 0; ks < 2; ++ks) {
        const int r = wc * 64 + n * 16 + lr;
        bfr[n][ks] = *(const bf16x8*)((const char*)Bs + r * 128 +
                                      ((ks * 64 + lk * 16) ^ ((r & 7) << 4)));
      }
    __builtin_amdgcn_s_setprio(1);
#pragma unroll
    for (int m = 0; m < 4; ++m)
#pragma unroll
      for (int n = 0; n < 4; ++n)
#pragma unroll
        for (int ks = 0; ks < 2; ++ks)
          acc[m][n] = __builtin_amdgcn_mfma_f32_16x16x32_bf16(
              af[m][ks], bfr[n][ks], acc[m][n], 0, 0, 0);
    __builtin_amdgcn_s_setprio(0);
    __syncthreads();
  }

#pragma unroll
  for (int m = 0; m < 4; ++m)
#pragma unroll
    for (int n = 0; n < 4; ++n)
#pragma unroll
      for (int r4 = 0; r4 < 4; ++r4) {
        const int row = m0 + wr * 64 + m * 16 + lk * 4 + r4;
        const int col = n0 + wc * 64 + n * 16 + lr;
        float v = acc[m][n][r4] + bias[col];
        if (OUT_BF16)
          ((bf16*)Cout)[(size_t)row * N + col] = __float2bfloat16(v);
        else
          ((float*)Cout)[(size_t)row * N + col] = v;
      }
}

template <int OUT_BF16>
__launch_bounds__(256, 2)
__global__ void gemm_bt(const bf16* __restrict__ A, const bf16* __restrict__ BT,
                        const float* __restrict__ bias, void* __restrict__ Cout,
                        int M, int N, int K) {
  gemm_body<OUT_BF16>(A, BT, bias, Cout, M, N, K, blockIdx.y * 128,
                      blockIdx.x * 128);
}

// fused Q/K/V projection: blockIdx.z selects the GEMM
__launch_bounds__(256, 2)
__global__ void gemm_qkv(const bf16* __restrict__ qb, const bf16* __restrict__ kb,
                         const bf16* __restrict__ vb, const bf16* __restrict__ WqT,
                         const bf16* __restrict__ WkT, const bf16* __restrict__ WvT,
                         const float* __restrict__ bq, const float* __restrict__ bk,
                         const float* __restrict__ bv, bf16* __restrict__ qp,
                         bf16* __restrict__ kp, bf16* __restrict__ vp) {
  const int z = blockIdx.z;
  const bf16* A = (z == 0) ? qb : (z == 1) ? kb : vb;
  const bf16* BT = (z == 0) ? WqT : (z == 1) ? WkT : WvT;
  const float* bias = (z == 0) ? bq : (z == 1) ? bk : bv;
  bf16* C = (z == 0) ? qp : (z == 1) ? kp : vp;
  const int M = (z == 0) ? (B_ * LQ_) : (B_ * LKV_);
  const int K = (z == 0) ? QDIM_ : KDIM_;
  const int m0 = blockIdx.y * 128;
  if (m0 >= M) return;
  gemm_body<1>(A, BT, bias, C, M, ODIM_, K, m0, blockIdx.x * 128);
}

// ---------------------------------------------------------------------------
// Flash attention v5: sigma-permuted K rows + in-register softmax (verified in
// v3) with LDS-STAGED DOUBLE-BUFFERED K/V via global_load_lds (no dest regs ->
// loads issue back-to-back; counted vmcnt(4) + 2 barriers/tile; tile shared by
// all 4 waves -> 4x fewer L2 reads). XOR-swizzled both-sides (4-way residual).
// Mask row for batch b staged to LDS once (broadcast reads).
// Grid: 512 blocks, d%8 = XCD; 8 (b,h) pairs per XCD -> K/V set = 4MB = L2.
// ---------------------------------------------------------------------------
__launch_bounds__(256, 2)
__global__ void attn5(const bf16* __restrict__ qp, const bf16* __restrict__ kp,
                      const bf16* __restrict__ vT, const float* __restrict__ mf,
                      bf16* __restrict__ att) {
  __shared__ bf16 Ks[2][64 * 64];   // [buf][kv][hd] swizzled, 8KB each
  __shared__ bf16 Vs[2][64 * 64];   // [buf][hd][kv] swizzled, 8KB each
  __shared__ float Ms[LKV_];        // mask row for batch b, 8KB
  const int tid = threadIdx.x;
  const int w = tid >> 6, l = tid & 63;
  const int l31 = l & 31, hi = l >> 5;
  const int d = blockIdx.x;
  const int hb = (d & 7) * 8 + ((d >> 3) & 7);  // XCD-chunked (b,h)
  const int qt = d >> 6;
  const int h = hb & 15, b = hb >> 4;
  const int q0 = qt * 128 + w * 32;

  // sigma: A-row m (=l31) reads LDS K row sigma(m)
  const int rr = (l31 & 3) + 4 * (l31 >> 3);
  const int hh = (l31 >> 2) & 1;
  const int sig = (rr < 8) ? (8 * hh + rr) : (8 + 8 * hh + rr);

  // stage mask row (2048 floats, 8KB): 2 x 16B per thread
  {
    const float* msrc = mf + b * LKV_;
    async_cp16(msrc + tid * 4, &Ms[tid * 4]);
    async_cp16(msrc + 1024 + tid * 4, &Ms[1024 + tid * 4]);
  }

  // Q fragments (B-operand): lane holds Q[q0+l31][hd = ks*16 + hi*8 + j]
  bf16x8 qf[4];
  {
    const bf16* qbp =
        qp + (size_t)(b * LQ_ + q0 + l31) * ODIM_ + h * HD_ + hi * 8;
#pragma unroll
    for (int ks = 0; ks < 4; ++ks) qf[ks] = *(const bf16x8*)(qbp + ks * 16);
  }

  const int NT = LKV_ / 64;  // 32
  // stage tile t into buffer buf: K 8KB + V 8KB = 4 x 16B per thread
  auto stage = [&](int t, int buf) {
    const int kv0 = (t & (NT - 1)) * 64;
#pragma unroll
    for (int i = 0; i < 2; ++i) {
      const int c = tid + i * 256;
      const int row = c >> 3, cc = c & 7, sc = cc ^ (row & 7);
      async_cp16(kp + (size_t)(b * LKV_ + kv0 + row) * ODIM_ + h * HD_ + sc * 8,
                 &Ks[buf][c * 8]);
    }
#pragma unroll
    for (int i = 0; i < 2; ++i) {
      const int c = tid + i * 256;
      const int row = c >> 3, cc = c & 7, sc = cc ^ (row & 7);
      async_cp16(vT + (size_t)((b * H_ + h) * HD_ + row) * LKV_ + kv0 + sc * 8,
                 &Vs[buf][c * 8]);
    }
  };

  f32x16 oacc0, oacc1;
#pragma unroll
  for (int r = 0; r < 16; ++r) { oacc0[r] = 0.f; oacc1[r] = 0.f; }
  float m_ = -1e30f, l_ = 0.f;
  const float csc = 0.125f * 1.4426950408889634f;  // scale * log2(e)

  stage(0, 0);
  for (int t = 0; t < NT; ++t) {
    const int buf = t & 1;
    stage(t + 1, buf ^ 1);
    asm volatile("s_waitcnt vmcnt(4)" ::: "memory");  // own tile-t loads done
    __syncthreads();                                  // whole tile t in LDS

    // ---- QK^T from LDS (rows sig / sig+32, chunk = ks*2+hi, XOR swizzle)
    f32x16 s0, s1;
#pragma unroll
    for (int r = 0; r < 16; ++r) { s0[r] = 0.f; s1[r] = 0.f; }
    __builtin_amdgcn_s_setprio(1);
#pragma unroll
    for (int ks = 0; ks < 4; ++ks) {
      const int ch = ks * 2 + hi;
      bf16x8 k0 = *(const bf16x8*)((const char*)&Ks[buf][0] + sig * 128 +
                                   ((ch ^ (sig & 7)) * 16));
      const int s2 = sig + 32;
      bf16x8 k1 = *(const bf16x8*)((const char*)&Ks[buf][0] + s2 * 128 +
                                   ((ch ^ (s2 & 7)) * 16));
      s0 = __builtin_amdgcn_mfma_f32_32x32x16_bf16(k0, qf[ks], s0, 0, 0, 0);
      s1 = __builtin_amdgcn_mfma_f32_32x32x16_bf16(k1, qf[ks], s1, 0, 0, 0);
    }
    __builtin_amdgcn_s_setprio(0);

    // ---- mask multipliers from LDS (broadcast reads)
    const int mb = t * 64 + hi * 8;
    f32x4 mq0[4], mq1[4];
    mq0[0] = *(const f32x4*)&Ms[mb + 0];
    mq0[1] = *(const f32x4*)&Ms[mb + 4];
    mq0[2] = *(const f32x4*)&Ms[mb + 16];
    mq0[3] = *(const f32x4*)&Ms[mb + 20];
    mq1[0] = *(const f32x4*)&Ms[mb + 32];
    mq1[1] = *(const f32x4*)&Ms[mb + 36];
    mq1[2] = *(const f32x4*)&Ms[mb + 48];
    mq1[3] = *(const f32x4*)&Ms[mb + 52];

    // ---- row max over the 64 kv of this tile (order-agnostic)
    float rm = s0[0];
#pragma unroll
    for (int r = 1; r < 16; ++r) rm = fmaxf(rm, s0[r]);
#pragma unroll
    for (int r = 0; r < 16; ++r) rm = fmaxf(rm, s1[r]);
    rm = fmaxf(rm, __shfl_xor(rm, 32));
    const float pm = rm * csc;

    // ---- defer-max rescale (rare; wave-uniform branch)
    if (__any(pm > m_ + 11.0f)) {
      const float mn = fmaxf(m_, pm);
      const float alpha = fast_exp2(m_ - mn);
      l_ *= alpha;
      m_ = mn;
#pragma unroll
      for (int r = 0; r < 16; ++r) {
        const float av = __shfl(alpha, (r & 3) + 8 * (r >> 2) + 4 * hi);
        oacc0[r] *= av;
        oacc1[r] *= av;
      }
    }

    // ---- p = 2^(s*c - m) * mask ; row sum
    float psum = 0.f;
#pragma unroll
    for (int r = 0; r < 16; ++r) {
      float p0 = fast_exp2(fmaf(s0[r], csc, -m_)) * mq0[r >> 2][r & 3];
      float p1 = fast_exp2(fmaf(s1[r], csc, -m_)) * mq1[r >> 2][r & 3];
      s0[r] = p0;
      s1[r] = p1;
      psum += p0 + p1;
    }
    psum += __shfl_xor(psum, 32);
    l_ += psum;

    // ---- pack P into PV A-frags: pure lane-local cvt_pk
    bf16x8 pa[4];
    pa[0] = make_frag(cvtpk(s0[0], s0[1]), cvtpk(s0[2], s0[3]),
                      cvtpk(s0[4], s0[5]), cvtpk(s0[6], s0[7]));
    pa[1] = make_frag(cvtpk(s0[8], s0[9]), cvtpk(s0[10], s0[11]),
                      cvtpk(s0[12], s0[13]), cvtpk(s0[14], s0[15]));
    pa[2] = make_frag(cvtpk(s1[0], s1[1]), cvtpk(s1[2], s1[3]),
                      cvtpk(s1[4], s1[5]), cvtpk(s1[6], s1[7]));
    pa[3] = make_frag(cvtpk(s1[8], s1[9]), cvtpk(s1[10], s1[11]),
                      cvtpk(s1[12], s1[13]), cvtpk(s1[14], s1[15]));

    // ---- O += P @ V from LDS (rows l31 / l31+32)
    __builtin_amdgcn_s_setprio(1);
#pragma unroll
    for (int ks = 0; ks < 4; ++ks) {
      const int ch = ks * 2 + hi;
      bf16x8 v0 = *(const bf16x8*)((const char*)&Vs[buf][0] + l31 * 128 +
                                   ((ch ^ (l31 & 7)) * 16));
      const int r2 = l31 + 32;
      bf16x8 v1 = *(const bf16x8*)((const char*)&Vs[buf][0] + r2 * 128 +
                                   ((ch ^ (r2 & 7)) * 16));
      oacc0 = __builtin_amdgcn_mfma_f32_32x32x16_bf16(pa[ks], v0, oacc0, 0, 0, 0);
      oacc1 = __builtin_amdgcn_mfma_f32_32x32x16_bf16(pa[ks], v1, oacc1, 0, 0, 0);
    }
    __builtin_amdgcn_s_setprio(0);
    __syncthreads();  // all waves done reading buf before it is restaged
  }

  // ---- epilogue: O /= l ; store bf16
  const float linv = 1.0f / l_;
  const size_t obase = (size_t)(b * LQ_ + q0) * ODIM_ + h * HD_;
#pragma unroll
  for (int r = 0; r < 16; ++r) {
    const int cr = (r & 3) + 8 * (r >> 2) + 4 * hi;
    const float lv = __shfl(linv, cr);
    att[obase + (size_t)cr * ODIM_ + l31] = __float2bfloat16(oacc0[r] * lv);
    att[obase + (size_t)cr * ODIM_ + 32 + l31] = __float2bfloat16(oacc1[r] * lv);
  }
}

// ---------------------------------------------------------------------------
extern "C" void kernel_launch(void* const* d_in, const int* in_sizes, int n_in,
                              void* d_out, int out_size, void* d_ws,
                              size_t ws_size, hipStream_t stream) {
  const float* query = (const float*)d_in[0];
  const float* key   = (const float*)d_in[1];
  const float* value = (const float*)d_in[2];
  const void* mask_raw = d_in[3];
  const float* Wq = (const float*)d_in[4];
  const float* bq = (const float*)d_in[5];
  const float* Wk = (const float*)d_in[6];
  const float* bk = (const float*)d_in[7];
  const float* Wv = (const float*)d_in[8];
  const float* bv = (const float*)d_in[9];
  const float* Wo = (const float*)d_in[10];
  const float* bo = (const float*)d_in[11];
  float* out = (float*)d_out;

  char* ws = (char*)d_ws;
  bf16* qb  = (bf16*)(ws + 0);          // 4096x1024   [0, 8388608)
  bf16* att = qb;                       // alias (qb dead after gemm-Q)
  bf16* kb  = (bf16*)(ws + 8388608);    // 8192x768
  bf16* vb  = (bf16*)(ws + 20971520);   // 8192x768
  bf16* vT  = (bf16*)(ws + 16777216);   // [B][H][64][2048] alias over kb tail
  bf16* WqT = (bf16*)(ws + 33554432);
  bf16* WkT = (bf16*)(ws + 35651584);
  bf16* WvT = (bf16*)(ws + 37224448);
  bf16* WoT = (bf16*)(ws + 38797312);
  bf16* qp  = (bf16*)(ws + 40894464);
  bf16* kp  = (bf16*)(ws + 49283072);
  bf16* vp  = (bf16*)(ws + 66060288);
  float* mf = (float*)(ws + 82837504);  // 8192 floats

  mask_prep<<<32, 256, 0, stream>>>(mask_raw, mf, B_ * LKV_);

  cvt3<<<dim3(6144, 3), 256, 0, stream>>>(query, key, value, qb, kb, vb);

  wtrans4<<<dim3(16, 16, 4), 256, 0, stream>>>(Wq, Wk, Wv, Wo,
                                               WqT, WkT, WvT, WoT);

  gemm_qkv<<<dim3(8, 64, 3), 256, 0, stream>>>(qb, kb, vb, WqT, WkT, WvT,
                                               bq, bk, bv, qp, kp, vp);

  vtrans<<<dim3(32, 16, 4), 256, 0, stream>>>(vp, vT);

  attn5<<<512, 256, 0, stream>>>(qp, kp, vT, mf, att);

  gemm_bt<0><<<dim3(8, 32), 256, 0, stream>>>(att, WoT, bo, out,
                                              B_ * LQ_, ODIM_, ODIM_);
}